// Round 1
// baseline (50.103 us; speedup 1.0000x reference)
//
#include <hip/hip_runtime.h>
#include <math.h>

// Problem constants (match reference)
constexpr int B = 4, S = 128, D = 256, TC = D * 4; // TC = 1024 (d,c flattened)
constexpr float EPS = 1e-6f;
constexpr int TI = 4; // query rows per block in attn kernel

// ---------------------------------------------------------------------------
// Kernel 1: compute real-space Q, K^T, V from LNS parameters.
//   Q[b,s,d,c]  = max(query[b,s,c], EPS) + exp(qw[c,s,d]) + exp(qb[d,c])
//   (same for K, V).  K stored transposed: Kt[b, t, s] with t = d*4+c,
//   so the score kernel reads are coalesced over s(=j).
// ---------------------------------------------------------------------------
__global__ __launch_bounds__(256)
void qlns_prep(const float* __restrict__ query,
               const float* __restrict__ key_in,
               const float* __restrict__ value,
               const float* __restrict__ qw, const float* __restrict__ qb,
               const float* __restrict__ kw, const float* __restrict__ kb,
               const float* __restrict__ vw, const float* __restrict__ vb,
               float* __restrict__ Q, float* __restrict__ Kt,
               float* __restrict__ V)
{
    int idx = blockIdx.x * blockDim.x + threadIdx.x;
    if (idx >= B * S * D * 4) return;
    int c = idx & 3;
    int d = (idx >> 2) & (D - 1);
    int s = (idx >> 10) & (S - 1);
    int b = idx >> 17;
    int t = d * 4 + c;

    int xi = (b * S + s) * 4 + c;   // [B,S,4]
    int wi = (c * S + s) * D + d;   // [4,S,D]
    int bi = d * 4 + c;             // [D,4]

    float q = fmaxf(query[xi], EPS)  + __expf(0.f) * 0.f + expf(qw[wi]) + expf(qb[bi]);
    float k = fmaxf(key_in[xi], EPS) + expf(kw[wi]) + expf(kb[bi]);
    float v = fmaxf(value[xi], EPS)  + expf(vw[wi]) + expf(vb[bi]);

    Q [(b * S + s) * TC + t] = q;
    Kt[(b * TC + t) * S + s] = k;
    V [(b * S + s) * TC + t] = v;
}

// ---------------------------------------------------------------------------
// Kernel 2: per block: batch b, TI consecutive query rows.
//   scores[ti][j] = sum_t Qrow[ti][t] * Kt[b][t][j]
//   attn = max(softmax_j(scores), EPS)      (the _to_log clamp)
//   out[ti][t]   = sum_j attn[ti][j] * V[b][j][t]
// 256 threads. LDS: Q rows (16KB) + partial scores (4KB) + attn (2KB).
// ---------------------------------------------------------------------------
__global__ __launch_bounds__(256)
void qlns_attn(const float* __restrict__ Q,
               const float* __restrict__ Kt,
               const float* __restrict__ V,
               float* __restrict__ out)
{
    __shared__ float qlds[TI][TC];     // 16 KB
    __shared__ float sc[2][TI][S];     // 4 KB partial scores (two t-halves)
    __shared__ float attn[TI][S];      // 2 KB

    const int blk = blockIdx.x;            // 0 .. B*S/TI-1
    const int b   = blk / (S / TI);
    const int i0  = (blk % (S / TI)) * TI;
    const int tid = threadIdx.x;

    // ---- load Q rows into LDS (coalesced) ----
    const float* Qbase = Q + (size_t)(b * S + i0) * TC;
    #pragma unroll
    for (int r = 0; r < TI * TC / 256; ++r) {
        int off = r * 256 + tid;
        qlds[off / TC][off % TC] = Qbase[off];
    }
    __syncthreads();

    // ---- scores: thread (half, j) accumulates TI dots over its t-half ----
    const int j    = tid & (S - 1);
    const int half = tid >> 7;             // 0 or 1
    float acc[TI];
    #pragma unroll
    for (int ti = 0; ti < TI; ++ti) acc[ti] = 0.f;

    const float* Ktb = Kt + (size_t)b * TC * S;
    const int t0 = half * (TC / 2), t1 = t0 + TC / 2;
    for (int t = t0; t < t1; ++t) {
        float kv = Ktb[t * S + j];
        #pragma unroll
        for (int ti = 0; ti < TI; ++ti) acc[ti] += qlds[ti][t] * kv;
    }
    #pragma unroll
    for (int ti = 0; ti < TI; ++ti) sc[half][ti][j] = acc[ti];
    __syncthreads();

    // ---- softmax: wave w handles row w (TI == 4 waves) ----
    {
        const int w    = tid >> 6;
        const int lane = tid & 63;
        float s0 = sc[0][w][lane]      + sc[1][w][lane];
        float s1 = sc[0][w][lane + 64] + sc[1][w][lane + 64];
        float m = fmaxf(s0, s1);
        #pragma unroll
        for (int o = 32; o > 0; o >>= 1) m = fmaxf(m, __shfl_xor(m, o));
        float e0 = expf(s0 - m), e1 = expf(s1 - m);
        float sum = e0 + e1;
        #pragma unroll
        for (int o = 32; o > 0; o >>= 1) sum += __shfl_xor(sum, o);
        float inv = 1.f / sum;
        attn[w][lane]      = fmaxf(e0 * inv, EPS);
        attn[w][lane + 64] = fmaxf(e1 * inv, EPS);
    }
    __syncthreads();

    // ---- output: thread owns 4 t-positions (t = tid + 256*r) ----
    float oacc[TI][4];
    #pragma unroll
    for (int ti = 0; ti < TI; ++ti)
        #pragma unroll
        for (int r = 0; r < 4; ++r) oacc[ti][r] = 0.f;

    const float* Vb = V + (size_t)b * S * TC;
    for (int jj = 0; jj < S; ++jj) {
        float a[TI];
        #pragma unroll
        for (int ti = 0; ti < TI; ++ti) a[ti] = attn[ti][jj];
        #pragma unroll
        for (int r = 0; r < 4; ++r) {
            float v = Vb[jj * TC + r * 256 + tid];
            #pragma unroll
            for (int ti = 0; ti < TI; ++ti) oacc[ti][r] += a[ti] * v;
        }
    }

    float* ob = out + (size_t)(b * S + i0) * TC;
    #pragma unroll
    for (int ti = 0; ti < TI; ++ti)
        #pragma unroll
        for (int r = 0; r < 4; ++r)
            ob[ti * TC + r * 256 + tid] = oacc[ti][r];
}

extern "C" void kernel_launch(void* const* d_in, const int* in_sizes, int n_in,
                              void* d_out, int out_size, void* d_ws, size_t ws_size,
                              hipStream_t stream)
{
    const float* query  = (const float*)d_in[0];
    const float* key_in = (const float*)d_in[1];
    const float* value  = (const float*)d_in[2];
    const float* qw = (const float*)d_in[3];
    const float* qb = (const float*)d_in[4];
    const float* kw = (const float*)d_in[5];
    const float* kb = (const float*)d_in[6];
    const float* vw = (const float*)d_in[7];
    const float* vb = (const float*)d_in[8];
    float* out = (float*)d_out;

    // workspace layout: Q (2MB) | Kt (2MB) | V (2MB)
    float* Q  = (float*)d_ws;
    float* Kt = Q  + (size_t)B * S * TC;
    float* V  = Kt + (size_t)B * TC * S;

    const int total = B * S * D * 4;
    qlns_prep<<<(total + 255) / 256, 256, 0, stream>>>(
        query, key_in, value, qw, qb, kw, kb, vw, vb, Q, Kt, V);

    qlns_attn<<<B * S / TI, 256, 0, stream>>>(Q, Kt, V, out);
}

// Round 2
// 35.162 us; speedup vs baseline: 1.4249x; 1.4249x over previous
//
#include <hip/hip_runtime.h>
#include <math.h>

// Problem constants (match reference)
constexpr int B = 4, S = 128, D = 256, TC = 1024;  // TC = D*4 (d,c flattened)
constexpr float EPS = 1e-6f;
constexpr int KS = 16, KW = 64;       // split-K config for G (KS*KW = TC)
constexpr int ROWS = 8, TCOLS = 256;  // fused-kernel tiling

// ---------------------------------------------------------------------------
// ws layout (floats):
//   Wq [S][TC] | Wk [S][TC] | Wv [S][TC] | SWq [S][4] | SWk [S][4]
//   | Gpart [KS][S][S]
// Everything fully rewritten each call (ws is poisoned once, never restored).
// ---------------------------------------------------------------------------

// K1: Wx[s,t] = exp(xw[c,s,d]) + exp(xb[d,c]);  SWq/SWk[s,c] = sum_d Wx[s,d*4+c]
__global__ __launch_bounds__(256)
void k1_prep(const float* __restrict__ qw, const float* __restrict__ qb,
             const float* __restrict__ kw, const float* __restrict__ kb,
             const float* __restrict__ vw, const float* __restrict__ vb,
             float* __restrict__ Wq, float* __restrict__ Wk, float* __restrict__ Wv,
             float* __restrict__ SWq, float* __restrict__ SWk)
{
    __shared__ float redq[256], redk[256];
    const int s = blockIdx.x, tid = threadIdx.x;
    float pq = 0.f, pk = 0.f;
    #pragma unroll
    for (int r = 0; r < 4; ++r) {
        int t = r * 256 + tid;
        int c = t & 3, d = t >> 2;
        int wi = (c * S + s) * D + d;      // [4,S,D]
        float a1 = expf(qw[wi]) + expf(qb[t]);   // qb: [D,4] flat == t
        float a2 = expf(kw[wi]) + expf(kb[t]);
        float a3 = expf(vw[wi]) + expf(vb[t]);
        Wq[s * TC + t] = a1; Wk[s * TC + t] = a2; Wv[s * TC + t] = a3;
        pq += a1; pk += a2;
    }
    redq[tid] = pq; redk[tid] = pk;
    __syncthreads();
    if (tid < 4) {  // c = tid; threads with tid%4==c contributed to this c
        float sq = 0.f, sk = 0.f;
        for (int u = tid; u < 256; u += 4) { sq += redq[u]; sk += redk[u]; }
        SWq[s * 4 + tid] = sq; SWk[s * 4 + tid] = sk;
    }
}

// K2: Gpart[ks][i][j] = sum_{k in slice ks} Wq[i,k]*Wk[j,k]
// grid (8 itiles, KS ksplits), 256 threads; LDS-staged, padded vs bank conflict
__global__ __launch_bounds__(256)
void k2_g(const float* __restrict__ Wq, const float* __restrict__ Wk,
          float* __restrict__ Gpart)
{
    __shared__ float wkT[KW][S + 1];    // [64][129] ~33KB, transposed
    __shared__ float wqs[16][KW + 1];   // [16][65]
    const int it = blockIdx.x, ks = blockIdx.y, tid = threadIdx.x;
    const int k0 = ks * KW;
    for (int e = tid; e < S * KW; e += 256) {
        int j = e >> 6, kk = e & 63;
        wkT[kk][j] = Wk[j * TC + k0 + kk];          // coalesced read, pad-safe write
    }
    for (int e = tid; e < 16 * KW; e += 256) {
        int i = e >> 6, kk = e & 63;
        wqs[i][kk] = Wq[(it * 16 + i) * TC + k0 + kk];
    }
    __syncthreads();
    const int j = tid & 127, ih = tid >> 7;
    float acc[8] = {0.f,0.f,0.f,0.f,0.f,0.f,0.f,0.f};
    for (int k = 0; k < KW; ++k) {
        float kv = wkT[k][j];                        // consecutive lanes, no conflict
        #pragma unroll
        for (int r = 0; r < 8; ++r) acc[r] += wqs[ih * 8 + r][k] * kv;  // broadcast
    }
    #pragma unroll
    for (int r = 0; r < 8; ++r) {
        int i = it * 16 + ih * 8 + r;
        Gpart[(ks * S + i) * S + j] = acc[r];        // coalesced over j
    }
}

// K3: fused scores (factorized) + softmax + PV for (b, 8 rows, 256 t-cols)
__global__ __launch_bounds__(256)
void k3_attn(const float* __restrict__ query, const float* __restrict__ key_in,
             const float* __restrict__ value,
             const float* __restrict__ Wv, const float* __restrict__ SWq,
             const float* __restrict__ SWk, const float* __restrict__ Gpart,
             float* __restrict__ out)
{
    __shared__ float att[ROWS][S];                  // scores -> attn (4KB)
    __shared__ float xkl[S][4], xvl[S][4], swkl[S][4];
    __shared__ float xql[ROWS][4], swql[ROWS][4];
    const int tt = blockIdx.x, i0 = blockIdx.y * ROWS, b = blockIdx.z;
    const int tid = threadIdx.x;

    for (int e = tid; e < S * 4; e += 256) {
        xkl[e >> 2][e & 3]  = fmaxf(key_in[b * S * 4 + e], EPS);
        xvl[e >> 2][e & 3]  = fmaxf(value[b * S * 4 + e], EPS);
        swkl[e >> 2][e & 3] = SWk[e];
    }
    if (tid < ROWS * 4) {
        xql[tid >> 2][tid & 3]  = fmaxf(query[(b * S + i0) * 4 + tid], EPS);
        swql[tid >> 2][tid & 3] = SWq[i0 * 4 + tid];
    }
    __syncthreads();

    // scores[i][j] = sum_ks Gpart + sum_c { D*xq*xk + xq*SWk[j] + SWq[i]*xk }
    for (int e = tid; e < ROWS * S; e += 256) {
        int i = e >> 7, j = e & 127;
        float g = 0.f;
        #pragma unroll
        for (int ks = 0; ks < KS; ++ks) g += Gpart[(ks * S + i0 + i) * S + j];
        float sc = g;
        #pragma unroll
        for (int c = 0; c < 4; ++c)
            sc += (float)D * xql[i][c] * xkl[j][c]
                + xql[i][c] * swkl[j][c] + swql[i][c] * xkl[j][c];
        att[i][j] = sc;
    }
    __syncthreads();

    // softmax over j per row; wave w handles rows w and w+4
    {
        const int w = tid >> 6, lane = tid & 63;
        #pragma unroll
        for (int rr = 0; rr < ROWS / 4; ++rr) {
            int i = w + rr * 4;
            float s0 = att[i][lane], s1 = att[i][lane + 64];
            float m = fmaxf(s0, s1);
            #pragma unroll
            for (int o = 32; o > 0; o >>= 1) m = fmaxf(m, __shfl_xor(m, o));
            float e0 = expf(s0 - m), e1 = expf(s1 - m);
            float sum = e0 + e1;
            #pragma unroll
            for (int o = 32; o > 0; o >>= 1) sum += __shfl_xor(sum, o);
            float inv = 1.f / sum;
            att[i][lane]      = fmaxf(e0 * inv, EPS);   // _to_log(attn) clamp
            att[i][lane + 64] = fmaxf(e1 * inv, EPS);
        }
    }
    __syncthreads();

    // PV: out[b,i,t] = sum_j attn[i][j] * (Wv[j,t] + xv[j,c(t)])
    const int t = tt * TCOLS + tid;
    const int c = t & 3;
    float acc[ROWS];
    #pragma unroll
    for (int i = 0; i < ROWS; ++i) acc[i] = 0.f;
    for (int j = 0; j < S; ++j) {
        float v = Wv[j * TC + t] + xvl[j][c];        // coalesced + LDS broadcast
        #pragma unroll
        for (int i = 0; i < ROWS; ++i) acc[i] += att[i][j] * v;
    }
    float* ob = out + (size_t)(b * S + i0) * TC + t;
    #pragma unroll
    for (int i = 0; i < ROWS; ++i) ob[i * TC] = acc[i];
}

extern "C" void kernel_launch(void* const* d_in, const int* in_sizes, int n_in,
                              void* d_out, int out_size, void* d_ws, size_t ws_size,
                              hipStream_t stream)
{
    const float* query  = (const float*)d_in[0];
    const float* key_in = (const float*)d_in[1];
    const float* value  = (const float*)d_in[2];
    const float* qw = (const float*)d_in[3];
    const float* qb = (const float*)d_in[4];
    const float* kw = (const float*)d_in[5];
    const float* kb = (const float*)d_in[6];
    const float* vw = (const float*)d_in[7];
    const float* vb = (const float*)d_in[8];
    float* out = (float*)d_out;

    float* Wq    = (float*)d_ws;
    float* Wk    = Wq + (size_t)S * TC;
    float* Wv    = Wk + (size_t)S * TC;
    float* SWq   = Wv + (size_t)S * TC;
    float* SWk   = SWq + S * 4;
    float* Gpart = SWk + S * 4;          // [KS][S][S] = 1 MB

    k1_prep<<<S, 256, 0, stream>>>(qw, qb, kw, kb, vw, vb, Wq, Wk, Wv, SWq, SWk);
    k2_g<<<dim3(S / 16, KS), 256, 0, stream>>>(Wq, Wk, Gpart);
    k3_attn<<<dim3(TC / TCOLS, S / ROWS, B), 256, 0, stream>>>(
        query, key_in, value, Wv, SWq, SWk, Gpart, out);
}